// Round 7
// baseline (192.277 us; speedup 1.0000x reference)
//
#include <hip/hip_runtime.h>

// SpikingLayer forward: first-spike times of a delayed-synapse LIF layer.
// B=128, I=512+1 bias, O=512, STEPS=200.
// R6: occupancy fix. R5's snn (~35us) was stuck at 3 blocks/CU (53KB LDS)
// -> grid needs 4/CU -> two ragged rounds at 67% util + only 6 waves/SIMD
// hiding cold-L2 load latency (the 268MB ws poison sweep flushes L2 every
// iteration). Time-split charge: bins 0..143 in LDS (arrivals are <=
// 0.01+delay ~ bin 135 at 5sigma; 144 ~ 8sigma), 39.5KB -> 4 blocks/CU,
// 32 waves, one exact round. Rare pass B (any lane unspiked at t=144):
// re-zero 56 rows, re-scan synapses for s>=144, integrate the tail.
// Arithmetic bit-identical to R5 (deterministic int binning; same
// integration op sequence): IEEE-exact bin via f64 mul, contract off.

#define IN_F    512
#define OUT_F   512
#define BATCH   128
#define STEPS   200
#define SPLIT   144                          // LDS-resident bins [0,SPLIT)
#define ROWS_B  (STEPS - SPLIT)              // 56 tail bins
#define RES_F   1e-4f
#define CSTRIDE 65                           // stride-65: bank=(s+col)%32
// double exp(-1e-4/5e-3) = exp(-0.02), rounded to f32 by the literal:
#define DECAY_F 0.98019867330675525f
// double (1.0 - exp(-0.02)), rounded to f32:
#define ONEMD_F 0.019801326693244747f
#define SIM_T_F 2e-2f
#define FPSCALE 8388608.0f                   // 2^23
#define INVSCALE 1.1920928955078125e-07f     // 2^-23, exact

// q = fl32(arr / 1e-4f) computed exactly: (double)arr*10000.0 is exact
// (24+14 sig bits <= 53), double->float cvt is RNE == IEEE f32 division.
__device__ __forceinline__ int bin_of(float arr) {
    float q = (float)((double)arr * 10000.0);
    int s = __float2int_rn(q);               // RNE == np.round half-to-even
    s = s < 0 ? 0 : (s > STEPS - 1 ? STEPS - 1 : s);
    return s;
}

__global__ __launch_bounds__(256) void prep_wi(
    const float* __restrict__ weights, int* __restrict__ wI)
{
    int idx = blockIdx.x * 256 + threadIdx.x;        // float4 index
    if (idx < (IN_F + 1) * OUT_F / 4) {
        float4 v = ((const float4*)weights)[idx];
        int4 r;
        r.x = __float2int_rn(v.x * FPSCALE);
        r.y = __float2int_rn(v.y * FPSCALE);
        r.z = __float2int_rn(v.z * FPSCALE);
        r.w = __float2int_rn(v.w * FPSCALE);
        ((int4*)wI)[idx] = r;
    }
}

// One full synapse scan with depth-2 ping-pong loads; bins only events in
// this pass's step range. PASSB=false: s<SPLIT at row s. true: s>=SPLIT at
// row s-SPLIT.
template<bool PASSB>
__device__ __forceinline__ void bin_pass(
    const int4* __restrict__ Wp, const float4* __restrict__ Dp,
    const float* __restrict__ times_s, int* __restrict__ chargeI,
    int i0, int gstr, int r0, int sub, int cg)
{
    int4   wA = Wp[i0],            wB = Wp[i0 + gstr];
    float4 dA = Dp[i0],            dB = Dp[i0 + gstr];
    float  tA = times_s[r0 + sub];
    float  tB = times_s[r0 + 4 + sub];

    #pragma unroll
    for (int g = 0; g < 16; g += 2) {
        int4   wC = {}, wD = {};
        float4 dC = {}, dD = {};
        float  tC = 0.f, tD = 0.f;
        if (g + 2 < 16) {
            wC = Wp[i0 + (g + 2) * gstr]; dC = Dp[i0 + (g + 2) * gstr];
            tC = times_s[r0 + ((g + 2) << 2) + sub];
        }
        if (g + 3 < 16) {
            wD = Wp[i0 + (g + 3) * gstr]; dD = Dp[i0 + (g + 3) * gstr];
            tD = times_s[r0 + ((g + 3) << 2) + sub];
        }
        {   // consume step g
            const float* dv = (const float*)&dA;
            const int*   wi = (const int*)&wA;
            #pragma unroll
            for (int k = 0; k < 4; ++k) {
                int s = bin_of(tA + dv[k]);
                if (!PASSB) { if (s < SPLIT)
                    atomicAdd(&chargeI[s * CSTRIDE + cg + k], wi[k]); }
                else        { if (s >= SPLIT)
                    atomicAdd(&chargeI[(s - SPLIT) * CSTRIDE + cg + k], wi[k]); }
            }
        }
        {   // consume step g+1
            const float* dv = (const float*)&dB;
            const int*   wi = (const int*)&wB;
            #pragma unroll
            for (int k = 0; k < 4; ++k) {
                int s = bin_of(tB + dv[k]);
                if (!PASSB) { if (s < SPLIT)
                    atomicAdd(&chargeI[s * CSTRIDE + cg + k], wi[k]); }
                else        { if (s >= SPLIT)
                    atomicAdd(&chargeI[(s - SPLIT) * CSTRIDE + cg + k], wi[k]); }
            }
        }
        wA = wC; dA = dC; tA = tC;
        wB = wD; dB = dD; tB = tD;
    }
}

__global__ __launch_bounds__(512, 8) void snn_fwd(
    const float* __restrict__ input_times,   // [B, IN_F]
    const int*   __restrict__ wI,            // [IN_F+1, OUT_F] fixed-point
    const float* __restrict__ delays,        // [IN_F+1, OUT_F]
    const float* __restrict__ thresholds,    // [OUT_F]
    float* __restrict__ out)                 // [B, OUT_F]
{
#pragma clang fp contract(off)
    __shared__ __align__(16) int chargeI[SPLIT * CSTRIDE];   // 37440 B
    __shared__ float times_s[IN_F];                          // 2048 B
    __shared__ int alldone_s;

    const int tid  = threadIdx.x;
    const int wv   = tid >> 6;               // wave 0..7
    const int lane = tid & 63;
    const int b     = blockIdx.x >> 3;
    const int otile = blockIdx.x & 7;
    const int ob    = otile << 6;            // output-column base

    // zero charge bins (int4) + stage this batch's input times
    {
        int4 z = make_int4(0, 0, 0, 0);
        int4* c4 = (int4*)chargeI;
        #pragma unroll
        for (int k = tid; k < (SPLIT * CSTRIDE) / 4; k += 512) c4[k] = z;
    }
    times_s[tid] = input_times[b * IN_F + tid];   // IN_F == blockDim == 512
    __syncthreads();

    // --- Phase 1A: bin synapse charges, steps [0, SPLIT) ---
    const int sub = lane >> 4;               // 0..3
    const int cg  = (lane & 15) << 2;        // 0,4,...,60
    const int4*   __restrict__ Wp = (const int4*)wI;
    const float4* __restrict__ Dp = (const float4*)delays;
    const int r0   = wv << 6;                                // first row
    const int i0   = (r0 + sub) * (OUT_F / 4) + ((ob + cg) >> 2);
    const int gstr = 4 * (OUT_F / 4);                        // 4 rows of vec4s

    // bias row (i=512, spike time 0): wave 7, one column per lane
    if (wv == 7) {
        float dl = delays[IN_F * OUT_F + ob + lane];
        int   wt = wI[IN_F * OUT_F + ob + lane];
        int s = bin_of(dl);
        if (s < SPLIT) atomicAdd(&chargeI[s * CSTRIDE + lane], wt);
    }
    bin_pass<false>(Wp, Dp, times_s, chargeI, i0, gstr, r0, sub, cg);
    __syncthreads();

    // --- Phase 2A (wave 0): integrate steps 0..SPLIT-1 ---
    const float thr = (wv == 0) ? thresholds[ob + lane] : 0.f;
    float syn = 0.f, mem = 0.f, spike_t = SIM_T_F;
    bool spiked = false;
    if (wv == 0) {
        for (int t0 = 0; t0 < SPLIT; t0 += 4) {
            float c[4];
            #pragma unroll
            for (int j = 0; j < 4; ++j)
                c[j] = (float)chargeI[(t0 + j) * CSTRIDE + lane] * INVSCALE;
            #pragma unroll
            for (int j = 0; j < 4; ++j) {
                float syn_n = syn * DECAY_F + c[j];               // no fma
                float mem_n = mem * DECAY_F + ONEMD_F * syn_n;    // no fma
                if (!spiked && mem_n >= thr) {
                    float denom = mem_n - mem;
                    float safe  = fabsf(denom) > 1e-12f ? denom : 1e-12f;
                    float frac  = (thr - mem) / safe;
                    frac = frac < 0.f ? 0.f : (frac > 1.f ? 1.f : frac);
                    spike_t = ((float)(t0 + j) + frac) * RES_F;
                    spiked  = true;
                }
                syn = syn_n; mem = mem_n;
            }
            if (__all(spiked)) break;        // => alldone, tail never needed
        }
        int ad = __all(spiked) ? 1 : 0;      // wave-uniform
        if (lane == 0) alldone_s = ad;
    }
    __syncthreads();

    // --- Rare tail path: some lane unspiked at t=SPLIT ---
    if (!alldone_s) {
        {   // re-zero rows 0..ROWS_B-1 (reused for steps SPLIT..199)
            int4 z = make_int4(0, 0, 0, 0);
            int4* c4 = (int4*)chargeI;
            for (int k = tid; k < (ROWS_B * CSTRIDE) / 4; k += 512) c4[k] = z;
        }
        __syncthreads();
        if (wv == 7) {
            float dl = delays[IN_F * OUT_F + ob + lane];
            int   wt = wI[IN_F * OUT_F + ob + lane];
            int s = bin_of(dl);
            if (s >= SPLIT)
                atomicAdd(&chargeI[(s - SPLIT) * CSTRIDE + lane], wt);
        }
        bin_pass<true>(Wp, Dp, times_s, chargeI, i0, gstr, r0, sub, cg);
        __syncthreads();
        if (wv == 0) {
            // syn/mem are valid: alldone=0 implies no early break occurred
            for (int t0 = SPLIT; t0 < STEPS; t0 += 4) {
                float c[4];
                #pragma unroll
                for (int j = 0; j < 4; ++j)
                    c[j] = (float)chargeI[(t0 - SPLIT + j) * CSTRIDE + lane]
                           * INVSCALE;
                #pragma unroll
                for (int j = 0; j < 4; ++j) {
                    float syn_n = syn * DECAY_F + c[j];
                    float mem_n = mem * DECAY_F + ONEMD_F * syn_n;
                    if (!spiked && mem_n >= thr) {
                        float denom = mem_n - mem;
                        float safe  = fabsf(denom) > 1e-12f ? denom : 1e-12f;
                        float frac  = (thr - mem) / safe;
                        frac = frac < 0.f ? 0.f : (frac > 1.f ? 1.f : frac);
                        spike_t = ((float)(t0 + j) + frac) * RES_F;
                        spiked  = true;
                    }
                    syn = syn_n; mem = mem_n;
                }
                if (__all(spiked)) break;
            }
        }
    }
    if (wv == 0) out[b * OUT_F + ob + lane] = spike_t;
}

extern "C" void kernel_launch(void* const* d_in, const int* in_sizes, int n_in,
                              void* d_out, int out_size, void* d_ws, size_t ws_size,
                              hipStream_t stream) {
    const float* input_times = (const float*)d_in[0];   // [128, 512]
    const float* weights     = (const float*)d_in[1];   // [513, 512]
    const float* delays      = (const float*)d_in[2];   // [513, 512]
    const float* thresholds  = (const float*)d_in[3];   // [512]
    float* out = (float*)d_out;                         // [128, 512]
    int*   wI  = (int*)d_ws;                            // [513, 512] fixed-pt

    // prologue: weights -> fixed-point (runs every call; deterministic)
    int nvec4 = (IN_F + 1) * OUT_F / 4;                 // 65664
    prep_wi<<<(nvec4 + 255) / 256, 256, 0, stream>>>(weights, wI);

    dim3 grid(BATCH * (OUT_F / 64));   // 1024 blocks x 512 threads (8 waves)
    snn_fwd<<<grid, 512, 0, stream>>>(input_times, wI, delays, thresholds, out);
}